// Round 5
// baseline (625.772 us; speedup 1.0000x reference)
//
#include <hip/hip_runtime.h>

#define N_NODES 131072
#define E_EDGES 524288
#define B_GR    2048
#define H_DIM   128
#define NF_DIM  30
#define GF_DIM  4415
#define GF_PAD  4416            // 138*32
#define BN_SCALE 0.9999950000374997f   // 1/sqrt(1+1e-5)

typedef __bf16 bf16x8 __attribute__((ext_vector_type(8)));
typedef float  f32x4  __attribute__((ext_vector_type(4)));
typedef unsigned int uint32;
typedef uint32 u32x4 __attribute__((ext_vector_type(4)));

__device__ __forceinline__ void split2(float x, __bf16& hi, __bf16& lo){
    hi = (__bf16)x;
    lo = (__bf16)(x - (float)hi);
}
__device__ __forceinline__ uint32 bfbits(float x){
    __bf16 h = (__bf16)x;
    return (uint32)__builtin_bit_cast(unsigned short, h);
}
// packed uint32: low 16 bits = even col, high 16 bits = odd col
__device__ __forceinline__ float unpack_even(uint32 u){ return __uint_as_float(u<<16); }
__device__ __forceinline__ float unpack_odd (uint32 u){ return __uint_as_float(u & 0xffff0000u); }
__device__ __forceinline__ uint32 pack2(float e, float o){ return bfbits(e) | (bfbits(o)<<16); }

// ---------------- graph prep ----------------

__global__ void k_zero_int(int* __restrict__ p, int n){
    int i = blockIdx.x*256 + threadIdx.x;
    if(i < n) p[i] = 0;
}

__global__ void k_count(const int* __restrict__ dst, int* __restrict__ counts){
    int e = blockIdx.x*256 + threadIdx.x;
    if(e < E_EDGES) atomicAdd(&counts[dst[e]], 1);
}

__global__ void k_scan1(int* __restrict__ counts, int* __restrict__ bsums){
    __shared__ int s[1024];
    int t = threadIdx.x;
    int gi = blockIdx.x*1024 + t;
    int v = counts[gi];
    s[t] = v; __syncthreads();
    for(int off=1; off<1024; off<<=1){
        int x = (t>=off) ? s[t-off] : 0;
        __syncthreads();
        s[t] += x;
        __syncthreads();
    }
    counts[gi] = s[t] - v;
    if(t == 1023) bsums[blockIdx.x] = s[t];
}

__global__ void k_scan2(int* __restrict__ bsums){
    __shared__ int s[128];
    int t = threadIdx.x;
    int v = bsums[t]; s[t] = v; __syncthreads();
    for(int off=1; off<128; off<<=1){
        int x = (t>=off) ? s[t-off] : 0;
        __syncthreads();
        s[t] += x;
        __syncthreads();
    }
    bsums[t] = s[t] - v;
}

__global__ void k_scan3(const int* __restrict__ counts, const int* __restrict__ bsums,
                        int* __restrict__ rowptr){
    int i = blockIdx.x*1024 + threadIdx.x;
    rowptr[i] = counts[i] + bsums[blockIdx.x];
    if(i == 0) rowptr[N_NODES] = E_EDGES;
}

__global__ void k_dinv_cursor(const int* __restrict__ rowptr, float* __restrict__ dinv,
                              int* __restrict__ cursor){
    int n = blockIdx.x*256 + threadIdx.x;
    if(n < N_NODES){
        int a = rowptr[n], b = rowptr[n+1];
        dinv[n] = rsqrtf((float)(b - a) + 1.0f);
        cursor[n] = a;
    }
}

__global__ void k_fill(const int* __restrict__ src, const int* __restrict__ dst,
                       int* __restrict__ cursor, int* __restrict__ csr){
    int e = blockIdx.x*256 + threadIdx.x;
    if(e < E_EDGES){
        int p = atomicAdd(&cursor[dst[e]], 1);
        csr[p] = src[e];
    }
}

// ---------------- combined weight split: Wge1 + Wg + Wemb ----------------

__global__ void k_split_weights(const float* __restrict__ Wge1, __bf16* __restrict__ wth,
                                __bf16* __restrict__ wtl,
                                const float* __restrict__ Wg, __bf16* __restrict__ gth,
                                __bf16* __restrict__ gtl,
                                const float* __restrict__ Wemb, __bf16* __restrict__ eth,
                                __bf16* __restrict__ etl){
    unsigned bid = blockIdx.x;
    if(bid < 4416u){
        unsigned idx = bid*256 + threadIdx.x;        // 256*4416 (c-major, k padded)
        unsigned c = idx / GF_PAD, k = idx - c*GF_PAD;
        float v = (k < GF_DIM) ? Wge1[(size_t)k*256 + c] : 0.f;
        split2(v, wth[idx], wtl[idx]);
    } else if(bid < 4416u + 192u){
        int idx = (bid - 4416u)*256 + threadIdx.x;   // 3*128*128
        int l = idx >> 14, i = idx & 16383;
        int k = i >> 7, c = i & 127;
        float v = Wg[idx];
        int o = (l << 14) + (c << 7) + k;            // transposed: [l][c][k]
        split2(v, gth[o], gtl[o]);
    } else {
        int idx = (bid - 4608u)*256 + threadIdx.x;   // 128*32  (c-major, k padded)
        int c = idx >> 5, k = idx & 31;
        float v = (k < NF_DIM) ? Wemb[k*H_DIM + c] : 0.f;
        split2(v, eth[idx], etl[idx]);
    }
}

// ---------------- embedding via MFMA (fused x split):  relu(x @ W_emb + b) ----------------

__global__ __launch_bounds__(256)
void k_emb_mfma(const float* __restrict__ x,
                const __bf16* __restrict__ wth, const __bf16* __restrict__ wtl,
                const float* __restrict__ bias, uint32* __restrict__ Hh2,
                uint32* __restrict__ Hl2){
    __shared__ float sT[4][32*68];
    int wave = threadIdx.x >> 6, lane = threadIdx.x & 63;
    int lr = lane & 15, lq = lane >> 4;
    int rbase = blockIdx.x*128 + wave*32;
    const f32x4 zero4 = {0.f,0.f,0.f,0.f};
    const float* xr0 = x + (size_t)(rbase + lr)*NF_DIM;
    const float* xr1 = x + (size_t)(rbase + 16 + lr)*NF_DIM;
    bf16x8 A0h, A0l, A1h, A1l;
    #pragma unroll
    for(int t=0;t<8;t++){
        int k = lq*8 + t;
        float v0 = (k < NF_DIM) ? xr0[k] : 0.f;
        float v1 = (k < NF_DIM) ? xr1[k] : 0.f;
        __bf16 h, l;
        split2(v0, h, l); A0h[t] = h; A0l[t] = l;
        split2(v1, h, l); A1h[t] = h; A1l[t] = l;
    }
    int orow = lane >> 3;          // 0..7
    int oq   = lane & 7;           // 0..7
    float* sW = sT[wave];
    for(int ph=0; ph<2; ph++){
        #pragma unroll
        for(int cc=0; cc<4; cc++){
            int col = (ph*4+cc)*16 + lr;
            bf16x8 Bh = *(const bf16x8*)(wth + col*32 + lq*8);
            bf16x8 Bl = *(const bf16x8*)(wtl + col*32 + lq*8);
            f32x4 a0 = zero4, a1 = zero4;
            a0 = __builtin_amdgcn_mfma_f32_16x16x32_bf16(A0h, Bh, a0, 0,0,0);
            a0 = __builtin_amdgcn_mfma_f32_16x16x32_bf16(A0l, Bh, a0, 0,0,0);
            a0 = __builtin_amdgcn_mfma_f32_16x16x32_bf16(A0h, Bl, a0, 0,0,0);
            a1 = __builtin_amdgcn_mfma_f32_16x16x32_bf16(A1h, Bh, a1, 0,0,0);
            a1 = __builtin_amdgcn_mfma_f32_16x16x32_bf16(A1l, Bh, a1, 0,0,0);
            a1 = __builtin_amdgcn_mfma_f32_16x16x32_bf16(A1h, Bl, a1, 0,0,0);
            #pragma unroll
            for(int r=0;r<4;r++){
                sW[(lq*4+r)*68 + cc*16 + lr]    = a0[r];
                sW[(16+lq*4+r)*68 + cc*16 + lr] = a1[r];
            }
        }
        __syncthreads();
        int cg = ph*64 + oq*8;
        float bb[8];
        *(float4*)&bb[0] = *(const float4*)(bias + cg);
        *(float4*)&bb[4] = *(const float4*)(bias + cg + 4);
        #pragma unroll
        for(int i=0;i<4;i++){
            int row = i*8 + orow;
            float v[8];
            *(float4*)&v[0] = *(float4*)&sW[row*68 + oq*8];
            *(float4*)&v[4] = *(float4*)&sW[row*68 + oq*8 + 4];
            uint32 oh[4], ol[4];
            #pragma unroll
            for(int p=0;p<4;p++){
                float ve = fmaxf(v[2*p]   + bb[2*p],   0.f);
                float vo = fmaxf(v[2*p+1] + bb[2*p+1], 0.f);
                uint32 he = bfbits(ve), ho = bfbits(vo);
                oh[p] = he | (ho<<16);
                float le = ve - __uint_as_float(he<<16);
                float lo = vo - __uint_as_float(ho<<16);
                ol[p] = pack2(le, lo);
            }
            size_t oidx = (size_t)(rbase + row)*64 + (cg>>1);
            *(uint4*)(Hh2 + oidx) = make_uint4(oh[0],oh[1],oh[2],oh[3]);
            *(uint4*)(Hl2 + oidx) = make_uint4(ol[0],ol[1],ol[2],ol[3]);
        }
        __syncthreads();
    }
}

// ---------------- FUSED GCN layer (unchanged): gather -> LDS -> MFMA -> epilogue ----

struct AggMeta {
    int   j0A, cA, j0B, cB;
    float dnA, dnB;
    uint32 shA, slA, shB, slB;
    int   jjA[8], jjB[8];
};

__device__ __forceinline__ void agg_load_meta(AggMeta& m, int nA, int lane,
                                              const int* __restrict__ rowptr,
                                              const float* __restrict__ dinv,
                                              const uint32* __restrict__ Hh2,
                                              const uint32* __restrict__ Hl2){
    int nB = nA + 8;
    int a0 = rowptr[nA], a1 = rowptr[nA+1];
    int b0 = rowptr[nB], b1 = rowptr[nB+1];
    m.j0A = a0; m.cA = a1 - a0;
    m.j0B = b0; m.cB = b1 - b0;
    m.dnA = dinv[nA]; m.dnB = dinv[nB];
    size_t iA = (size_t)nA*64 + lane, iB = (size_t)nB*64 + lane;
    m.shA = Hh2[iA]; m.slA = Hl2[iA];
    m.shB = Hh2[iB]; m.slB = Hl2[iB];
}

__device__ __forceinline__ void agg_load_csr(AggMeta& m, const int* __restrict__ csr){
    int jmA = m.j0A + m.cA - 1;
    int jmB = m.j0B + m.cB - 1;
    #pragma unroll
    for(int t=0;t<8;t++){
        int ia = m.j0A + t; ia = ia > jmA ? jmA : ia;
        int ib = m.j0B + t; ib = ib > jmB ? jmB : ib;
        m.jjA[t] = csr[ia] & (N_NODES-1);
        m.jjB[t] = csr[ib] & (N_NODES-1);
    }
}

__device__ __forceinline__ void agg_pair(AggMeta& cur, AggMeta& nxt, int ii, bool pf,
                                         int rbase, int base16, int lane,
                                         const uint32* __restrict__ Hh2,
                                         const uint32* __restrict__ Hl2,
                                         const float* __restrict__ dinv,
                                         const int* __restrict__ rowptr,
                                         const int* __restrict__ csr,
                                         uint32* __restrict__ AhL,
                                         uint32* __restrict__ AlL){
    uint32 rrA[8], rrB[8];
    float  wwA[8], wwB[8];
    #pragma unroll
    for(int t=0;t<8;t++){
        wwA[t] = (t < cur.cA) ? dinv[cur.jjA[t]] : 0.f;
        rrA[t] = Hh2[(size_t)cur.jjA[t]*64 + lane];
        wwB[t] = (t < cur.cB) ? dinv[cur.jjB[t]] : 0.f;
        rrB[t] = Hh2[(size_t)cur.jjB[t]*64 + lane];
    }
    if(pf){
        agg_load_meta(nxt, rbase + base16 + ii + 1, lane, rowptr, dinv, Hh2, Hl2);
        agg_load_csr(nxt, csr);
    }
    float axA = (unpack_even(cur.shA) + unpack_even(cur.slA)) * cur.dnA;
    float ayA = (unpack_odd(cur.shA)  + unpack_odd(cur.slA))  * cur.dnA;
    float axB = (unpack_even(cur.shB) + unpack_even(cur.slB)) * cur.dnB;
    float ayB = (unpack_odd(cur.shB)  + unpack_odd(cur.slB))  * cur.dnB;
    #pragma unroll
    for(int t=0;t<8;t++){
        axA = fmaf(unpack_even(rrA[t]), wwA[t], axA);
        ayA = fmaf(unpack_odd(rrA[t]),  wwA[t], ayA);
        axB = fmaf(unpack_even(rrB[t]), wwB[t], axB);
        ayB = fmaf(unpack_odd(rrB[t]),  wwB[t], ayB);
    }
    int nb = cur.cA > cur.cB ? cur.cA : cur.cB;
    if(nb > 8){
        int jmA = cur.j0A + cur.cA - 1;
        int jmB = cur.j0B + cur.cB - 1;
        for(int j=8; j<nb; j+=8){
            int jja[8], jjb[8]; float wa[8], wb[8]; uint32 ra[8], rb[8];
            #pragma unroll
            for(int t=0;t<8;t++){
                int ia = cur.j0A + j + t; ia = ia > jmA ? jmA : ia;
                int ib = cur.j0B + j + t; ib = ib > jmB ? jmB : ib;
                jja[t] = csr[ia] & (N_NODES-1);
                jjb[t] = csr[ib] & (N_NODES-1);
            }
            #pragma unroll
            for(int t=0;t<8;t++){
                wa[t] = (j + t < cur.cA) ? dinv[jja[t]] : 0.f;
                ra[t] = Hh2[(size_t)jja[t]*64 + lane];
                wb[t] = (j + t < cur.cB) ? dinv[jjb[t]] : 0.f;
                rb[t] = Hh2[(size_t)jjb[t]*64 + lane];
            }
            #pragma unroll
            for(int t=0;t<8;t++){
                axA = fmaf(unpack_even(ra[t]), wa[t], axA);
                ayA = fmaf(unpack_odd(ra[t]),  wa[t], ayA);
                axB = fmaf(unpack_even(rb[t]), wb[t], axB);
                ayB = fmaf(unpack_odd(rb[t]),  wb[t], ayB);
            }
        }
    }
    axA *= cur.dnA; ayA *= cur.dnA;
    axB *= cur.dnB; ayB *= cur.dnB;
    int rowA = base16 + ii, rowB = rowA + 8;
    uint32 hxA = bfbits(axA), hyA = bfbits(ayA);
    AhL[rowA*68 + lane] = hxA | (hyA<<16);
    AlL[rowA*68 + lane] = pack2(axA - __uint_as_float(hxA<<16),
                                ayA - __uint_as_float(hyA<<16));
    uint32 hxB = bfbits(axB), hyB = bfbits(ayB);
    AhL[rowB*68 + lane] = hxB | (hyB<<16);
    AlL[rowB*68 + lane] = pack2(axB - __uint_as_float(hxB<<16),
                                ayB - __uint_as_float(hyB<<16));
}

__global__ __launch_bounds__(512, 4)
void k_layer(const __bf16* __restrict__ curHh, const __bf16* __restrict__ curHl,
             const float* __restrict__ dinv, const int* __restrict__ rowptr,
             const int* __restrict__ csr,
             const __bf16* __restrict__ Bth, const __bf16* __restrict__ Btl,
             const float* __restrict__ bias, const float* __restrict__ gamma,
             const float* __restrict__ beta,
             uint32* __restrict__ outHh2, uint32* __restrict__ outHl2, int residual){
    __shared__ uint32 smem[8*32*68];              // 69632 B; A-region then reused as staging
    uint32* AhL = smem;
    uint32* AlL = smem + 128*68;
    int tid  = threadIdx.x;
    int wave = __builtin_amdgcn_readfirstlane(tid >> 6);
    int lane = tid & 63;
    int rbase = blockIdx.x * 128;
    int base16 = wave*16;
    const uint32* Hh2 = (const uint32*)curHh;
    const uint32* Hl2 = (const uint32*)curHl;

    {
        AggMeta m0, m1;
        agg_load_meta(m0, rbase + base16 + 0, lane, rowptr, dinv, Hh2, Hl2);
        agg_load_csr(m0, csr);
        agg_pair(m0, m1, 0, true,  rbase, base16, lane, Hh2, Hl2, dinv, rowptr, csr, AhL, AlL);
        agg_pair(m1, m0, 1, true,  rbase, base16, lane, Hh2, Hl2, dinv, rowptr, csr, AhL, AlL);
        agg_pair(m0, m1, 2, true,  rbase, base16, lane, Hh2, Hl2, dinv, rowptr, csr, AhL, AlL);
        agg_pair(m1, m0, 3, true,  rbase, base16, lane, Hh2, Hl2, dinv, rowptr, csr, AhL, AlL);
        agg_pair(m0, m1, 4, true,  rbase, base16, lane, Hh2, Hl2, dinv, rowptr, csr, AhL, AlL);
        agg_pair(m1, m0, 5, true,  rbase, base16, lane, Hh2, Hl2, dinv, rowptr, csr, AhL, AlL);
        agg_pair(m0, m1, 6, true,  rbase, base16, lane, Hh2, Hl2, dinv, rowptr, csr, AhL, AlL);
        agg_pair(m1, m0, 7, false, rbase, base16, lane, Hh2, Hl2, dinv, rowptr, csr, AhL, AlL);
    }
    __syncthreads();

    int lr = lane & 15, lq = lane >> 4;
    int wr = wave & 3, wc = wave >> 2;
    int r0 = wr*32;
    bf16x8 A0h[4], A0l[4], A1h[4], A1l[4];
    #pragma unroll
    for(int ks=0;ks<4;ks++){
        int u0 = (r0 + lr)*68 + lq*4 + ks*16;
        int u1 = (r0 + 16 + lr)*68 + lq*4 + ks*16;
        A0h[ks] = __builtin_bit_cast(bf16x8, *(const u32x4*)(AhL + u0));
        A0l[ks] = __builtin_bit_cast(bf16x8, *(const u32x4*)(AlL + u0));
        A1h[ks] = __builtin_bit_cast(bf16x8, *(const u32x4*)(AhL + u1));
        A1l[ks] = __builtin_bit_cast(bf16x8, *(const u32x4*)(AlL + u1));
    }
    __syncthreads();

    float* stg = (float*)smem + wave*(32*68);
    const f32x4 zero4 = {0.f,0.f,0.f,0.f};
    #pragma unroll
    for(int cc=0; cc<4; cc++){
        int col = wc*64 + cc*16 + lr;
        f32x4 a0 = zero4, a1 = zero4;
        #pragma unroll
        for(int ks=0;ks<4;ks++){
            bf16x8 Bh = *(const bf16x8*)(Bth + col*H_DIM + ks*32 + lq*8);
            bf16x8 Bl = *(const bf16x8*)(Btl + col*H_DIM + ks*32 + lq*8);
            a0 = __builtin_amdgcn_mfma_f32_16x16x32_bf16(A0h[ks], Bh, a0, 0,0,0);
            a0 = __builtin_amdgcn_mfma_f32_16x16x32_bf16(A0l[ks], Bh, a0, 0,0,0);
            a0 = __builtin_amdgcn_mfma_f32_16x16x32_bf16(A0h[ks], Bl, a0, 0,0,0);
            a1 = __builtin_amdgcn_mfma_f32_16x16x32_bf16(A1h[ks], Bh, a1, 0,0,0);
            a1 = __builtin_amdgcn_mfma_f32_16x16x32_bf16(A1l[ks], Bh, a1, 0,0,0);
            a1 = __builtin_amdgcn_mfma_f32_16x16x32_bf16(A1h[ks], Bl, a1, 0,0,0);
        }
        #pragma unroll
        for(int r=0;r<4;r++){
            stg[(lq*4+r)*68 + cc*16 + lr]    = a0[r];
            stg[(16+lq*4+r)*68 + cc*16 + lr] = a1[r];
        }
    }

    int orow = lane >> 3;
    int oq   = lane & 7;
    int cg = wc*64 + oq*8;
    float bb[8], gg[8], tt[8];
    *(float4*)&bb[0] = *(const float4*)(bias + cg);
    *(float4*)&bb[4] = *(const float4*)(bias + cg + 4);
    *(float4*)&gg[0] = *(const float4*)(gamma + cg);
    *(float4*)&gg[4] = *(const float4*)(gamma + cg + 4);
    *(float4*)&tt[0] = *(const float4*)(beta + cg);
    *(float4*)&tt[4] = *(const float4*)(beta + cg + 4);
    #pragma unroll
    for(int p=0;p<8;p++) gg[p] *= BN_SCALE;
    #pragma unroll
    for(int i=0;i<4;i++){
        int row = i*8 + orow;
        float v[8];
        *(float4*)&v[0] = *(float4*)&stg[row*68 + oq*8];
        *(float4*)&v[4] = *(float4*)&stg[row*68 + oq*8 + 4];
        size_t oidx = (size_t)(rbase + r0 + row)*64 + (cg>>1);
        uint4 oldh = {0,0,0,0}, oldl = {0,0,0,0};
        if(residual){
            oldh = *(const uint4*)(Hh2 + oidx);
            oldl = *(const uint4*)(Hl2 + oidx);
        }
        uint32 ohv[4] = {oldh.x,oldh.y,oldh.z,oldh.w};
        uint32 olv[4] = {oldl.x,oldl.y,oldl.z,oldl.w};
        uint32 oh[4], ol[4];
        #pragma unroll
        for(int p=0;p<4;p++){
            float ve = fmaxf(fmaf(v[2*p]   + bb[2*p],   gg[2*p],   tt[2*p]),   0.f);
            float vo = fmaxf(fmaf(v[2*p+1] + bb[2*p+1], gg[2*p+1], tt[2*p+1]), 0.f);
            if(residual){
                ve += unpack_even(ohv[p]) + unpack_even(olv[p]);
                vo += unpack_odd(ohv[p])  + unpack_odd(olv[p]);
            }
            uint32 he = bfbits(ve), ho = bfbits(vo);
            oh[p] = he | (ho<<16);
            float le = ve - __uint_as_float(he<<16);
            float lo = vo - __uint_as_float(ho<<16);
            ol[p] = pack2(le, lo);
        }
        *(uint4*)(outHh2 + oidx) = make_uint4(oh[0],oh[1],oh[2],oh[3]);
        *(uint4*)(outHl2 + oidx) = make_uint4(ol[0],ol[1],ol[2],ol[3]);
    }
}

// ---------------- gene GEMM via MFMA, fused A-split (fp32 -> hi/lo in-register) ----------------

__global__ __launch_bounds__(256)
void k_gemm_gf_mfma(const float* __restrict__ Agf,
                    const __bf16* __restrict__ Bth, const __bf16* __restrict__ Btl,
                    float* __restrict__ gpart){
    int rt = blockIdx.x & 31;       // 32 row tiles of 64
    int sp = blockIdx.x >> 5;       // 8 k-splits
    int ks0 = (sp*138) >> 3, ks1 = ((sp+1)*138) >> 3;
    int wave = threadIdx.x >> 6, lane = threadIdx.x & 63;
    int lr = lane & 15, lq = lane >> 4;
    int rbase = rt*64 + (wave & 1)*32;
    int cbase = (wave >> 1)*128;
    const f32x4 zero4 = {0.f,0.f,0.f,0.f};
    f32x4 acc[8][2];
    #pragma unroll
    for(int ct=0;ct<8;ct++){ acc[ct][0] = zero4; acc[ct][1] = zero4; }
    for(int ks=ks0; ks<ks1; ks++){
        int kc = ks*32;
        const float* ar0 = Agf + (size_t)(rbase + lr)*GF_DIM + kc + lq*8;
        const float* ar1 = ar0 + (size_t)16*GF_DIM;
        bf16x8 A0h, A0l, A1h, A1l;
        if(kc + 32 <= GF_DIM){
            #pragma unroll
            for(int t=0;t<8;t++){
                __bf16 h, l;
                split2(ar0[t], h, l); A0h[t] = h; A0l[t] = l;
                split2(ar1[t], h, l); A1h[t] = h; A1l[t] = l;
            }
        } else {
            #pragma unroll
            for(int t=0;t<8;t++){
                int k = kc + lq*8 + t;
                float v0 = 0.f, v1 = 0.f;
                if(k < GF_DIM){ v0 = ar0[t]; v1 = ar1[t]; }
                __bf16 h, l;
                split2(v0, h, l); A0h[t] = h; A0l[t] = l;
                split2(v1, h, l); A1h[t] = h; A1l[t] = l;
            }
        }
        #pragma unroll
        for(int ct=0;ct<8;ct++){
            size_t bo = (size_t)(cbase + ct*16 + lr)*GF_PAD + kc + lq*8;
            bf16x8 Bh = *(const bf16x8*)(Bth + bo);
            bf16x8 Bl = *(const bf16x8*)(Btl + bo);
            acc[ct][0] = __builtin_amdgcn_mfma_f32_16x16x32_bf16(A0h, Bh, acc[ct][0], 0,0,0);
            acc[ct][0] = __builtin_amdgcn_mfma_f32_16x16x32_bf16(A0l, Bh, acc[ct][0], 0,0,0);
            acc[ct][0] = __builtin_amdgcn_mfma_f32_16x16x32_bf16(A0h, Bl, acc[ct][0], 0,0,0);
            acc[ct][1] = __builtin_amdgcn_mfma_f32_16x16x32_bf16(A1h, Bh, acc[ct][1], 0,0,0);
            acc[ct][1] = __builtin_amdgcn_mfma_f32_16x16x32_bf16(A1l, Bh, acc[ct][1], 0,0,0);
            acc[ct][1] = __builtin_amdgcn_mfma_f32_16x16x32_bf16(A1h, Bl, acc[ct][1], 0,0,0);
        }
    }
    float* po = gpart + (size_t)sp*(B_GR*256);
    #pragma unroll
    for(int ct=0;ct<8;ct++)
        #pragma unroll
        for(int s=0;s<2;s++)
            #pragma unroll
            for(int r=0;r<4;r++)
                po[(size_t)(rbase + s*16 + lq*4 + r)*256 + cbase + ct*16 + lr] = acc[ct][s][r];
}

__global__ void k_gene_reduce(const float* __restrict__ gpart, const float* __restrict__ bias,
                              const float* __restrict__ gamma, const float* __restrict__ beta,
                              float* __restrict__ g1){
    int i = blockIdx.x*256 + threadIdx.x;   // B*256
    int c = i & 255;
    float v = bias[c];
    #pragma unroll
    for(int sp=0;sp<8;sp++) v += gpart[(size_t)sp*(B_GR*256) + i];
    v = fmaf(v, gamma[c]*BN_SCALE, beta[c]);
    g1[i] = fmaxf(v, 0.f);
}

// ---------------- FUSED head v2: 8 graphs/block, 512 threads; weight traffic amortized ----

__global__ __launch_bounds__(512)
void k_head(const uint32* __restrict__ Hh2, const uint32* __restrict__ Hl2,
            const float* __restrict__ g1,
            const float* __restrict__ Wd1, const float* __restrict__ bd1,
            const float* __restrict__ Wd2, const float* __restrict__ bd2,
            const float* __restrict__ Wge2, const float* __restrict__ bge2,
            const float* __restrict__ Wh1, const float* __restrict__ bh1,
            const float* __restrict__ h_g, const float* __restrict__ h_b,
            const float* __restrict__ Wh2, const float* __restrict__ bh2,
            const float* __restrict__ Wh3, const float* __restrict__ bh3,
            float* __restrict__ out){
    __shared__ float sPool[8][256];
    __shared__ float sG1[8][256];
    __shared__ float sT1[8][128];
    __shared__ float sComb[8][256];
    __shared__ float sZ[8][128];
    __shared__ float sZ2[8][64];
    int tid = threadIdx.x;
    int wave = tid >> 6, lane = tid & 63;
    int g0 = blockIdx.x*8;
    // g1 into LDS: 8*256 floats, float4 per thread
    {
        int idx = tid*4;                 // 0..2047
        int g = idx >> 8, c = idx & 255;
        *(float4*)&sG1[g][c] = *(const float4*)&g1[(size_t)(g0+g)*256 + c];
    }
    // pool: wave w owns graph w (64 rows, lane = uint-col)
    {
        size_t base = (size_t)(g0+wave)*4096 + lane;
        float se = 0.f, so = 0.f, me = -3.4e38f, mo = -3.4e38f;
        #pragma unroll 8
        for(int r=0;r<64;r++){
            uint32 h = Hh2[base + r*64];
            uint32 l = Hl2[base + r*64];
            float ve = unpack_even(h) + unpack_even(l);
            float vo = unpack_odd(h)  + unpack_odd(l);
            se += ve; so += vo;
            me = fmaxf(me, ve); mo = fmaxf(mo, vo);
        }
        sPool[wave][2*lane]       = se*(1.f/64.f);
        sPool[wave][2*lane+1]     = so*(1.f/64.f);
        sPool[wave][128+2*lane]   = me;
        sPool[wave][128+2*lane+1] = mo;
    }
    __syncthreads();
    int c = tid & 127, q = tid >> 7;     // q in 0..3 -> graphs 2q, 2q+1
    int ga = 2*q, gb = 2*q + 1;
    // t1 = relu(pool @ Wd1 + bd1)   K=256
    {
        float b = bd1[c];
        float a0 = b, a1 = b;
        #pragma unroll 4
        for(int k=0;k<256;k++){
            float w = Wd1[k*128 + c];
            a0 = fmaf(sPool[ga][k], w, a0);
            a1 = fmaf(sPool[gb][k], w, a1);
        }
        sT1[ga][c] = fmaxf(a0, 0.f);
        sT1[gb][c] = fmaxf(a1, 0.f);
    }
    __syncthreads();
    // comb = [ t1 @ Wd2 + bd2 (K=128) , relu(g1 @ Wge2 + bge2) (K=256) ]
    {
        float a0 = bd2[c], a1 = bd2[c];
        #pragma unroll 4
        for(int k=0;k<128;k++){
            float w = Wd2[k*128 + c];
            a0 = fmaf(sT1[ga][k], w, a0);
            a1 = fmaf(sT1[gb][k], w, a1);
        }
        sComb[ga][c] = a0;
        sComb[gb][c] = a1;
        float b0 = bge2[c], b1 = bge2[c];
        #pragma unroll 4
        for(int k=0;k<256;k++){
            float w = Wge2[k*128 + c];
            b0 = fmaf(sG1[ga][k], w, b0);
            b1 = fmaf(sG1[gb][k], w, b1);
        }
        sComb[ga][128 + c] = fmaxf(b0, 0.f);
        sComb[gb][128 + c] = fmaxf(b1, 0.f);
    }
    __syncthreads();
    // z = relu(BN(comb @ Wh1 + bh1))   K=256
    {
        float a0 = bh1[c], a1 = bh1[c];
        #pragma unroll 4
        for(int k=0;k<256;k++){
            float w = Wh1[k*128 + c];
            a0 = fmaf(sComb[ga][k], w, a0);
            a1 = fmaf(sComb[gb][k], w, a1);
        }
        float gs = h_g[c]*BN_SCALE, bs = h_b[c];
        sZ[ga][c] = fmaxf(fmaf(a0, gs, bs), 0.f);
        sZ[gb][c] = fmaxf(fmaf(a1, gs, bs), 0.f);
    }
    __syncthreads();
    // z2 = relu(z @ Wh2 + bh2)  N=64: 512 outputs = 512 threads, K=128
    {
        int c2 = tid & 63, q2 = tid >> 6;     // q2 = graph
        float a = bh2[c2];
        #pragma unroll 4
        for(int k=0;k<128;k++)
            a = fmaf(sZ[q2][k], Wh2[k*64 + c2], a);
        sZ2[q2][c2] = fmaxf(a, 0.f);
    }
    __syncthreads();
    // out = z2 @ Wh3 + bh3 : wave w -> graph w
    {
        float v = sZ2[wave][lane] * Wh3[lane];
        #pragma unroll
        for(int off=32; off; off>>=1) v += __shfl_down(v, off);
        if(lane == 0) out[g0 + wave] = v + bh3[0];
    }
}

// ---------------- launch ----------------

extern "C" void kernel_launch(void* const* d_in, const int* in_sizes, int n_in,
                              void* d_out, int out_size, void* d_ws, size_t ws_size,
                              hipStream_t stream){
    (void)in_sizes; (void)n_in; (void)out_size; (void)ws_size;
    const float* x    = (const float*)d_in[0];
    const float* gf   = (const float*)d_in[1];
    const int*   ei   = (const int*)  d_in[2];
    const float* W_emb= (const float*)d_in[4];
    const float* b_emb= (const float*)d_in[5];
    const float* Wg   = (const float*)d_in[6];
    const float* bg   = (const float*)d_in[7];
    const float* bn_g = (const float*)d_in[8];
    const float* bn_b = (const float*)d_in[9];
    const float* Wd1  = (const float*)d_in[10];
    const float* bd1  = (const float*)d_in[11];
    const float* Wd2  = (const float*)d_in[12];
    const float* bd2  = (const float*)d_in[13];
    const float* Wge1 = (const float*)d_in[14];
    const float* bge1 = (const float*)d_in[15];
    const float* g_g  = (const float*)d_in[16];
    const float* g_b  = (const float*)d_in[17];
    const float* Wge2 = (const float*)d_in[18];
    const float* bge2 = (const float*)d_in[19];
    const float* Wh1  = (const float*)d_in[20];
    const float* bh1  = (const float*)d_in[21];
    const float* h_g  = (const float*)d_in[22];
    const float* h_b  = (const float*)d_in[23];
    const float* Wh2  = (const float*)d_in[24];
    const float* bh2  = (const float*)d_in[25];
    const float* Wh3  = (const float*)d_in[26];
    const float* bh3  = (const float*)d_in[27];
    float* outp = (float*)d_out;

    char* base = (char*)d_ws;
    __bf16* Hh = (__bf16*)base;                              // 32 MiB (ping)
    __bf16* Hl = (__bf16*)(base + (32u<<20));                // 32 MiB
    __bf16* Ph = (__bf16*)(base + (64u<<20));                // 32 MiB (pong)
    __bf16* Pl = (__bf16*)(base + (96u<<20));                // 32 MiB
    // gene scratch inside Hh region (dead before k_emb_mfma runs; stream-ordered):
    float*  gpart  = (float*)base;                           // 16,777,216 B
    __bf16* wge_th = (__bf16*)(base + (17u<<20));            // 2,260,992 B
    __bf16* wge_tl = (__bf16*)(base + (17u<<20) + 2260992);  // ends < 22 MiB
    // tail:
    char* T = base + (128u<<20);
    float* g1   = (float*)T;                                 // 2 MiB
    int* rowptr = (int*)(g1 + B_GR*256);
    int* cursor = rowptr + (N_NODES+1);
    int* csr    = cursor + N_NODES;
    int* bsums  = csr + E_EDGES;
    float* dinv = (float*)(bsums + 128);
    __bf16* wg_th = (__bf16*)(dinv + N_NODES);               // 3*16384
    __bf16* wg_tl = wg_th + 3*16384;
    __bf16* we_th = wg_tl + 3*16384;                         // 128*32
    __bf16* we_tl = we_th + 128*32;

    const int* src = ei;
    const int* dst = ei + E_EDGES;

    // weights split (Wge1 + Wg + Wemb in one launch)
    k_split_weights<<<4624, 256, 0, stream>>>(Wge1, wge_th, wge_tl, Wg, wg_th, wg_tl,
                                              W_emb, we_th, we_tl);

    // gene branch (gpart/wge live in Hh region, consumed before k_emb)
    k_gemm_gf_mfma<<<256, 256, 0, stream>>>(gf, wge_th, wge_tl, gpart);
    k_gene_reduce <<<(B_GR*256)/256, 256, 0, stream>>>(gpart, bge1, g_g, g_b, g1);

    // graph prep
    k_zero_int   <<<N_NODES/256, 256, 0, stream>>>(cursor, N_NODES);
    k_count      <<<E_EDGES/256, 256, 0, stream>>>(dst, cursor);
    k_scan1      <<<128, 1024, 0, stream>>>(cursor, bsums);
    k_scan2      <<<1, 128, 0, stream>>>(bsums);
    k_scan3      <<<128, 1024, 0, stream>>>(cursor, bsums, rowptr);
    k_dinv_cursor<<<N_NODES/256, 256, 0, stream>>>(rowptr, dinv, cursor);
    k_fill       <<<E_EDGES/256, 256, 0, stream>>>(src, dst, cursor, csr);

    // embedding (fused x split)
    k_emb_mfma<<<N_NODES/128, 256, 0, stream>>>(x, we_th, we_tl, b_emb,
                                                (uint32*)Hh, (uint32*)Hl);

    // 3 fused GCN layers, ping-pong (Hh,Hl) <-> (Ph,Pl)
    uint32 *curh = (uint32*)Hh, *curl = (uint32*)Hl;
    uint32 *outh = (uint32*)Ph, *outl = (uint32*)Pl;
    for(int i=0;i<3;i++){
        k_layer<<<N_NODES/128, 512, 0, stream>>>((const __bf16*)curh, (const __bf16*)curl,
                                                 dinv, rowptr, csr,
                                                 wg_th + i*16384, wg_tl + i*16384,
                                                 bg + i*H_DIM, bn_g + i*H_DIM, bn_b + i*H_DIM,
                                                 outh, outl, i > 0);
        uint32* th = curh; curh = outh; outh = th;
        uint32* tl = curl; curl = outl; outl = tl;
    }

    // fused head v2 (8 graphs/block); final H is in (curh, curl)
    k_head<<<B_GR/8, 512, 0, stream>>>(curh, curl, g1,
                                       Wd1, bd1, Wd2, bd2, Wge2, bge2,
                                       Wh1, bh1, h_g, h_b, Wh2, bh2, Wh3, bh3, outp);
}

// Round 6
// 567.211 us; speedup vs baseline: 1.1032x; 1.1032x over previous
//
#include <hip/hip_runtime.h>

#define N_NODES 131072
#define E_EDGES 524288
#define B_GR    2048
#define H_DIM   128
#define NF_DIM  30
#define GF_DIM  4415
#define GF_PAD  4416            // 138*32
#define BN_SCALE 0.9999950000374997f   // 1/sqrt(1+1e-5)

typedef __bf16 bf16x8 __attribute__((ext_vector_type(8)));
typedef float  f32x4  __attribute__((ext_vector_type(4)));
typedef unsigned int uint32;
typedef uint32 u32x4 __attribute__((ext_vector_type(4)));

__device__ __forceinline__ void split2(float x, __bf16& hi, __bf16& lo){
    hi = (__bf16)x;
    lo = (__bf16)(x - (float)hi);
}
__device__ __forceinline__ uint32 bfbits(float x){
    __bf16 h = (__bf16)x;
    return (uint32)__builtin_bit_cast(unsigned short, h);
}
// packed uint32: low 16 bits = even col, high 16 bits = odd col
__device__ __forceinline__ float unpack_even(uint32 u){ return __uint_as_float(u<<16); }
__device__ __forceinline__ float unpack_odd (uint32 u){ return __uint_as_float(u & 0xffff0000u); }
__device__ __forceinline__ uint32 pack2(float e, float o){ return bfbits(e) | (bfbits(o)<<16); }

// ---------------- graph prep ----------------

__global__ void k_zero_int(int* __restrict__ p, int n){
    int i = blockIdx.x*256 + threadIdx.x;
    if(i < n) p[i] = 0;
}

__global__ void k_count(const int* __restrict__ dst, int* __restrict__ counts){
    int e = blockIdx.x*256 + threadIdx.x;
    if(e < E_EDGES) atomicAdd(&counts[dst[e]], 1);
}

__global__ void k_scan1(int* __restrict__ counts, int* __restrict__ bsums){
    __shared__ int s[1024];
    int t = threadIdx.x;
    int gi = blockIdx.x*1024 + t;
    int v = counts[gi];
    s[t] = v; __syncthreads();
    for(int off=1; off<1024; off<<=1){
        int x = (t>=off) ? s[t-off] : 0;
        __syncthreads();
        s[t] += x;
        __syncthreads();
    }
    counts[gi] = s[t] - v;
    if(t == 1023) bsums[blockIdx.x] = s[t];
}

__global__ void k_scan2(int* __restrict__ bsums){
    __shared__ int s[128];
    int t = threadIdx.x;
    int v = bsums[t]; s[t] = v; __syncthreads();
    for(int off=1; off<128; off<<=1){
        int x = (t>=off) ? s[t-off] : 0;
        __syncthreads();
        s[t] += x;
        __syncthreads();
    }
    bsums[t] = s[t] - v;
}

__global__ void k_scan3(const int* __restrict__ counts, const int* __restrict__ bsums,
                        int* __restrict__ rowptr){
    int i = blockIdx.x*1024 + threadIdx.x;
    rowptr[i] = counts[i] + bsums[blockIdx.x];
    if(i == 0) rowptr[N_NODES] = E_EDGES;
}

__global__ void k_dinv_cursor(const int* __restrict__ rowptr, float* __restrict__ dinv,
                              int* __restrict__ cursor){
    int n = blockIdx.x*256 + threadIdx.x;
    if(n < N_NODES){
        int a = rowptr[n], b = rowptr[n+1];
        dinv[n] = rsqrtf((float)(b - a) + 1.0f);
        cursor[n] = a;
    }
}

__global__ void k_fill(const int* __restrict__ src, const int* __restrict__ dst,
                       int* __restrict__ cursor, int* __restrict__ csr){
    int e = blockIdx.x*256 + threadIdx.x;
    if(e < E_EDGES){
        int p = atomicAdd(&cursor[dst[e]], 1);
        csr[p] = src[e];
    }
}

// ---------------- combined weight split: Wge1 + Wg + Wemb ----------------

__global__ void k_split_weights(const float* __restrict__ Wge1, __bf16* __restrict__ wth,
                                __bf16* __restrict__ wtl,
                                const float* __restrict__ Wg, __bf16* __restrict__ gth,
                                __bf16* __restrict__ gtl,
                                const float* __restrict__ Wemb, __bf16* __restrict__ eth,
                                __bf16* __restrict__ etl){
    unsigned bid = blockIdx.x;
    if(bid < 4416u){
        unsigned idx = bid*256 + threadIdx.x;        // 256*4416 (c-major, k padded)
        unsigned c = idx / GF_PAD, k = idx - c*GF_PAD;
        float v = (k < GF_DIM) ? Wge1[(size_t)k*256 + c] : 0.f;
        split2(v, wth[idx], wtl[idx]);
    } else if(bid < 4416u + 192u){
        int idx = (bid - 4416u)*256 + threadIdx.x;   // 3*128*128
        int l = idx >> 14, i = idx & 16383;
        int k = i >> 7, c = i & 127;
        float v = Wg[idx];
        int o = (l << 14) + (c << 7) + k;            // transposed: [l][c][k]
        split2(v, gth[o], gtl[o]);
    } else {
        int idx = (bid - 4608u)*256 + threadIdx.x;   // 128*32  (c-major, k padded)
        int c = idx >> 5, k = idx & 31;
        float v = (k < NF_DIM) ? Wemb[k*H_DIM + c] : 0.f;
        split2(v, eth[idx], etl[idx]);
    }
}

// ---------------- embedding via MFMA (fused x split):  relu(x @ W_emb + b) ----------------

__global__ __launch_bounds__(256)
void k_emb_mfma(const float* __restrict__ x,
                const __bf16* __restrict__ wth, const __bf16* __restrict__ wtl,
                const float* __restrict__ bias, uint32* __restrict__ Hh2,
                uint32* __restrict__ Hl2){
    __shared__ float sT[4][32*68];
    int wave = threadIdx.x >> 6, lane = threadIdx.x & 63;
    int lr = lane & 15, lq = lane >> 4;
    int rbase = blockIdx.x*128 + wave*32;
    const f32x4 zero4 = {0.f,0.f,0.f,0.f};
    const float* xr0 = x + (size_t)(rbase + lr)*NF_DIM;
    const float* xr1 = x + (size_t)(rbase + 16 + lr)*NF_DIM;
    bf16x8 A0h, A0l, A1h, A1l;
    #pragma unroll
    for(int t=0;t<8;t++){
        int k = lq*8 + t;
        float v0 = (k < NF_DIM) ? xr0[k] : 0.f;
        float v1 = (k < NF_DIM) ? xr1[k] : 0.f;
        __bf16 h, l;
        split2(v0, h, l); A0h[t] = h; A0l[t] = l;
        split2(v1, h, l); A1h[t] = h; A1l[t] = l;
    }
    int orow = lane >> 3;          // 0..7
    int oq   = lane & 7;           // 0..7
    float* sW = sT[wave];
    for(int ph=0; ph<2; ph++){
        #pragma unroll
        for(int cc=0; cc<4; cc++){
            int col = (ph*4+cc)*16 + lr;
            bf16x8 Bh = *(const bf16x8*)(wth + col*32 + lq*8);
            bf16x8 Bl = *(const bf16x8*)(wtl + col*32 + lq*8);
            f32x4 a0 = zero4, a1 = zero4;
            a0 = __builtin_amdgcn_mfma_f32_16x16x32_bf16(A0h, Bh, a0, 0,0,0);
            a0 = __builtin_amdgcn_mfma_f32_16x16x32_bf16(A0l, Bh, a0, 0,0,0);
            a0 = __builtin_amdgcn_mfma_f32_16x16x32_bf16(A0h, Bl, a0, 0,0,0);
            a1 = __builtin_amdgcn_mfma_f32_16x16x32_bf16(A1h, Bh, a1, 0,0,0);
            a1 = __builtin_amdgcn_mfma_f32_16x16x32_bf16(A1l, Bh, a1, 0,0,0);
            a1 = __builtin_amdgcn_mfma_f32_16x16x32_bf16(A1h, Bl, a1, 0,0,0);
            #pragma unroll
            for(int r=0;r<4;r++){
                sW[(lq*4+r)*68 + cc*16 + lr]    = a0[r];
                sW[(16+lq*4+r)*68 + cc*16 + lr] = a1[r];
            }
        }
        __syncthreads();
        int cg = ph*64 + oq*8;
        float bb[8];
        *(float4*)&bb[0] = *(const float4*)(bias + cg);
        *(float4*)&bb[4] = *(const float4*)(bias + cg + 4);
        #pragma unroll
        for(int i=0;i<4;i++){
            int row = i*8 + orow;
            float v[8];
            *(float4*)&v[0] = *(float4*)&sW[row*68 + oq*8];
            *(float4*)&v[4] = *(float4*)&sW[row*68 + oq*8 + 4];
            uint32 oh[4], ol[4];
            #pragma unroll
            for(int p=0;p<4;p++){
                float ve = fmaxf(v[2*p]   + bb[2*p],   0.f);
                float vo = fmaxf(v[2*p+1] + bb[2*p+1], 0.f);
                uint32 he = bfbits(ve), ho = bfbits(vo);
                oh[p] = he | (ho<<16);
                float le = ve - __uint_as_float(he<<16);
                float lo = vo - __uint_as_float(ho<<16);
                ol[p] = pack2(le, lo);
            }
            size_t oidx = (size_t)(rbase + row)*64 + (cg>>1);
            *(uint4*)(Hh2 + oidx) = make_uint4(oh[0],oh[1],oh[2],oh[3]);
            *(uint4*)(Hl2 + oidx) = make_uint4(ol[0],ol[1],ol[2],ol[3]);
        }
        __syncthreads();
    }
}

// ---------------- FUSED GCN layer (unchanged): gather -> LDS -> MFMA -> epilogue ----

struct AggMeta {
    int   j0A, cA, j0B, cB;
    float dnA, dnB;
    uint32 shA, slA, shB, slB;
    int   jjA[8], jjB[8];
};

__device__ __forceinline__ void agg_load_meta(AggMeta& m, int nA, int lane,
                                              const int* __restrict__ rowptr,
                                              const float* __restrict__ dinv,
                                              const uint32* __restrict__ Hh2,
                                              const uint32* __restrict__ Hl2){
    int nB = nA + 8;
    int a0 = rowptr[nA], a1 = rowptr[nA+1];
    int b0 = rowptr[nB], b1 = rowptr[nB+1];
    m.j0A = a0; m.cA = a1 - a0;
    m.j0B = b0; m.cB = b1 - b0;
    m.dnA = dinv[nA]; m.dnB = dinv[nB];
    size_t iA = (size_t)nA*64 + lane, iB = (size_t)nB*64 + lane;
    m.shA = Hh2[iA]; m.slA = Hl2[iA];
    m.shB = Hh2[iB]; m.slB = Hl2[iB];
}

__device__ __forceinline__ void agg_load_csr(AggMeta& m, const int* __restrict__ csr){
    int jmA = m.j0A + m.cA - 1;
    int jmB = m.j0B + m.cB - 1;
    #pragma unroll
    for(int t=0;t<8;t++){
        int ia = m.j0A + t; ia = ia > jmA ? jmA : ia;
        int ib = m.j0B + t; ib = ib > jmB ? jmB : ib;
        m.jjA[t] = csr[ia] & (N_NODES-1);
        m.jjB[t] = csr[ib] & (N_NODES-1);
    }
}

__device__ __forceinline__ void agg_pair(AggMeta& cur, AggMeta& nxt, int ii, bool pf,
                                         int rbase, int base16, int lane,
                                         const uint32* __restrict__ Hh2,
                                         const uint32* __restrict__ Hl2,
                                         const float* __restrict__ dinv,
                                         const int* __restrict__ rowptr,
                                         const int* __restrict__ csr,
                                         uint32* __restrict__ AhL,
                                         uint32* __restrict__ AlL){
    uint32 rrA[8], rrB[8];
    float  wwA[8], wwB[8];
    #pragma unroll
    for(int t=0;t<8;t++){
        wwA[t] = (t < cur.cA) ? dinv[cur.jjA[t]] : 0.f;
        rrA[t] = Hh2[(size_t)cur.jjA[t]*64 + lane];
        wwB[t] = (t < cur.cB) ? dinv[cur.jjB[t]] : 0.f;
        rrB[t] = Hh2[(size_t)cur.jjB[t]*64 + lane];
    }
    if(pf){
        agg_load_meta(nxt, rbase + base16 + ii + 1, lane, rowptr, dinv, Hh2, Hl2);
        agg_load_csr(nxt, csr);
    }
    float axA = (unpack_even(cur.shA) + unpack_even(cur.slA)) * cur.dnA;
    float ayA = (unpack_odd(cur.shA)  + unpack_odd(cur.slA))  * cur.dnA;
    float axB = (unpack_even(cur.shB) + unpack_even(cur.slB)) * cur.dnB;
    float ayB = (unpack_odd(cur.shB)  + unpack_odd(cur.slB))  * cur.dnB;
    #pragma unroll
    for(int t=0;t<8;t++){
        axA = fmaf(unpack_even(rrA[t]), wwA[t], axA);
        ayA = fmaf(unpack_odd(rrA[t]),  wwA[t], ayA);
        axB = fmaf(unpack_even(rrB[t]), wwB[t], axB);
        ayB = fmaf(unpack_odd(rrB[t]),  wwB[t], ayB);
    }
    int nb = cur.cA > cur.cB ? cur.cA : cur.cB;
    if(nb > 8){
        int jmA = cur.j0A + cur.cA - 1;
        int jmB = cur.j0B + cur.cB - 1;
        for(int j=8; j<nb; j+=8){
            int jja[8], jjb[8]; float wa[8], wb[8]; uint32 ra[8], rb[8];
            #pragma unroll
            for(int t=0;t<8;t++){
                int ia = cur.j0A + j + t; ia = ia > jmA ? jmA : ia;
                int ib = cur.j0B + j + t; ib = ib > jmB ? jmB : ib;
                jja[t] = csr[ia] & (N_NODES-1);
                jjb[t] = csr[ib] & (N_NODES-1);
            }
            #pragma unroll
            for(int t=0;t<8;t++){
                wa[t] = (j + t < cur.cA) ? dinv[jja[t]] : 0.f;
                ra[t] = Hh2[(size_t)jja[t]*64 + lane];
                wb[t] = (j + t < cur.cB) ? dinv[jjb[t]] : 0.f;
                rb[t] = Hh2[(size_t)jjb[t]*64 + lane];
            }
            #pragma unroll
            for(int t=0;t<8;t++){
                axA = fmaf(unpack_even(ra[t]), wa[t], axA);
                ayA = fmaf(unpack_odd(ra[t]),  wa[t], ayA);
                axB = fmaf(unpack_even(rb[t]), wb[t], axB);
                ayB = fmaf(unpack_odd(rb[t]),  wb[t], ayB);
            }
        }
    }
    axA *= cur.dnA; ayA *= cur.dnA;
    axB *= cur.dnB; ayB *= cur.dnB;
    int rowA = base16 + ii, rowB = rowA + 8;
    uint32 hxA = bfbits(axA), hyA = bfbits(ayA);
    AhL[rowA*68 + lane] = hxA | (hyA<<16);
    AlL[rowA*68 + lane] = pack2(axA - __uint_as_float(hxA<<16),
                                ayA - __uint_as_float(hyA<<16));
    uint32 hxB = bfbits(axB), hyB = bfbits(ayB);
    AhL[rowB*68 + lane] = hxB | (hyB<<16);
    AlL[rowB*68 + lane] = pack2(axB - __uint_as_float(hxB<<16),
                                ayB - __uint_as_float(hyB<<16));
}

__global__ __launch_bounds__(512, 4)
void k_layer(const __bf16* __restrict__ curHh, const __bf16* __restrict__ curHl,
             const float* __restrict__ dinv, const int* __restrict__ rowptr,
             const int* __restrict__ csr,
             const __bf16* __restrict__ Bth, const __bf16* __restrict__ Btl,
             const float* __restrict__ bias, const float* __restrict__ gamma,
             const float* __restrict__ beta,
             uint32* __restrict__ outHh2, uint32* __restrict__ outHl2, int residual){
    __shared__ uint32 smem[8*32*68];              // 69632 B; A-region then reused as staging
    uint32* AhL = smem;
    uint32* AlL = smem + 128*68;
    int tid  = threadIdx.x;
    int wave = __builtin_amdgcn_readfirstlane(tid >> 6);
    int lane = tid & 63;
    int rbase = blockIdx.x * 128;
    int base16 = wave*16;
    const uint32* Hh2 = (const uint32*)curHh;
    const uint32* Hl2 = (const uint32*)curHl;

    {
        AggMeta m0, m1;
        agg_load_meta(m0, rbase + base16 + 0, lane, rowptr, dinv, Hh2, Hl2);
        agg_load_csr(m0, csr);
        agg_pair(m0, m1, 0, true,  rbase, base16, lane, Hh2, Hl2, dinv, rowptr, csr, AhL, AlL);
        agg_pair(m1, m0, 1, true,  rbase, base16, lane, Hh2, Hl2, dinv, rowptr, csr, AhL, AlL);
        agg_pair(m0, m1, 2, true,  rbase, base16, lane, Hh2, Hl2, dinv, rowptr, csr, AhL, AlL);
        agg_pair(m1, m0, 3, true,  rbase, base16, lane, Hh2, Hl2, dinv, rowptr, csr, AhL, AlL);
        agg_pair(m0, m1, 4, true,  rbase, base16, lane, Hh2, Hl2, dinv, rowptr, csr, AhL, AlL);
        agg_pair(m1, m0, 5, true,  rbase, base16, lane, Hh2, Hl2, dinv, rowptr, csr, AhL, AlL);
        agg_pair(m0, m1, 6, true,  rbase, base16, lane, Hh2, Hl2, dinv, rowptr, csr, AhL, AlL);
        agg_pair(m1, m0, 7, false, rbase, base16, lane, Hh2, Hl2, dinv, rowptr, csr, AhL, AlL);
    }
    __syncthreads();

    int lr = lane & 15, lq = lane >> 4;
    int wr = wave & 3, wc = wave >> 2;
    int r0 = wr*32;
    bf16x8 A0h[4], A0l[4], A1h[4], A1l[4];
    #pragma unroll
    for(int ks=0;ks<4;ks++){
        int u0 = (r0 + lr)*68 + lq*4 + ks*16;
        int u1 = (r0 + 16 + lr)*68 + lq*4 + ks*16;
        A0h[ks] = __builtin_bit_cast(bf16x8, *(const u32x4*)(AhL + u0));
        A0l[ks] = __builtin_bit_cast(bf16x8, *(const u32x4*)(AlL + u0));
        A1h[ks] = __builtin_bit_cast(bf16x8, *(const u32x4*)(AhL + u1));
        A1l[ks] = __builtin_bit_cast(bf16x8, *(const u32x4*)(AlL + u1));
    }
    __syncthreads();

    float* stg = (float*)smem + wave*(32*68);
    const f32x4 zero4 = {0.f,0.f,0.f,0.f};
    #pragma unroll
    for(int cc=0; cc<4; cc++){
        int col = wc*64 + cc*16 + lr;
        f32x4 a0 = zero4, a1 = zero4;
        #pragma unroll
        for(int ks=0;ks<4;ks++){
            bf16x8 Bh = *(const bf16x8*)(Bth + col*H_DIM + ks*32 + lq*8);
            bf16x8 Bl = *(const bf16x8*)(Btl + col*H_DIM + ks*32 + lq*8);
            a0 = __builtin_amdgcn_mfma_f32_16x16x32_bf16(A0h[ks], Bh, a0, 0,0,0);
            a0 = __builtin_amdgcn_mfma_f32_16x16x32_bf16(A0l[ks], Bh, a0, 0,0,0);
            a0 = __builtin_amdgcn_mfma_f32_16x16x32_bf16(A0h[ks], Bl, a0, 0,0,0);
            a1 = __builtin_amdgcn_mfma_f32_16x16x32_bf16(A1h[ks], Bh, a1, 0,0,0);
            a1 = __builtin_amdgcn_mfma_f32_16x16x32_bf16(A1l[ks], Bh, a1, 0,0,0);
            a1 = __builtin_amdgcn_mfma_f32_16x16x32_bf16(A1h[ks], Bl, a1, 0,0,0);
        }
        #pragma unroll
        for(int r=0;r<4;r++){
            stg[(lq*4+r)*68 + cc*16 + lr]    = a0[r];
            stg[(16+lq*4+r)*68 + cc*16 + lr] = a1[r];
        }
    }

    int orow = lane >> 3;
    int oq   = lane & 7;
    int cg = wc*64 + oq*8;
    float bb[8], gg[8], tt[8];
    *(float4*)&bb[0] = *(const float4*)(bias + cg);
    *(float4*)&bb[4] = *(const float4*)(bias + cg + 4);
    *(float4*)&gg[0] = *(const float4*)(gamma + cg);
    *(float4*)&gg[4] = *(const float4*)(gamma + cg + 4);
    *(float4*)&tt[0] = *(const float4*)(beta + cg);
    *(float4*)&tt[4] = *(const float4*)(beta + cg + 4);
    #pragma unroll
    for(int p=0;p<8;p++) gg[p] *= BN_SCALE;
    #pragma unroll
    for(int i=0;i<4;i++){
        int row = i*8 + orow;
        float v[8];
        *(float4*)&v[0] = *(float4*)&stg[row*68 + oq*8];
        *(float4*)&v[4] = *(float4*)&stg[row*68 + oq*8 + 4];
        size_t oidx = (size_t)(rbase + r0 + row)*64 + (cg>>1);
        uint4 oldh = {0,0,0,0}, oldl = {0,0,0,0};
        if(residual){
            oldh = *(const uint4*)(Hh2 + oidx);
            oldl = *(const uint4*)(Hl2 + oidx);
        }
        uint32 ohv[4] = {oldh.x,oldh.y,oldh.z,oldh.w};
        uint32 olv[4] = {oldl.x,oldl.y,oldl.z,oldl.w};
        uint32 oh[4], ol[4];
        #pragma unroll
        for(int p=0;p<4;p++){
            float ve = fmaxf(fmaf(v[2*p]   + bb[2*p],   gg[2*p],   tt[2*p]),   0.f);
            float vo = fmaxf(fmaf(v[2*p+1] + bb[2*p+1], gg[2*p+1], tt[2*p+1]), 0.f);
            if(residual){
                ve += unpack_even(ohv[p]) + unpack_even(olv[p]);
                vo += unpack_odd(ohv[p])  + unpack_odd(olv[p]);
            }
            uint32 he = bfbits(ve), ho = bfbits(vo);
            oh[p] = he | (ho<<16);
            float le = ve - __uint_as_float(he<<16);
            float lo = vo - __uint_as_float(ho<<16);
            ol[p] = pack2(le, lo);
        }
        *(uint4*)(outHh2 + oidx) = make_uint4(oh[0],oh[1],oh[2],oh[3]);
        *(uint4*)(outHl2 + oidx) = make_uint4(ol[0],ol[1],ol[2],ol[3]);
    }
}

// ---------------- gene GEMM via MFMA, fused A-split (fp32 -> hi/lo in-register) ----------------

__global__ __launch_bounds__(256)
void k_gemm_gf_mfma(const float* __restrict__ Agf,
                    const __bf16* __restrict__ Bth, const __bf16* __restrict__ Btl,
                    float* __restrict__ gpart){
    int rt = blockIdx.x & 31;       // 32 row tiles of 64
    int sp = blockIdx.x >> 5;       // 8 k-splits
    int ks0 = (sp*138) >> 3, ks1 = ((sp+1)*138) >> 3;
    int wave = threadIdx.x >> 6, lane = threadIdx.x & 63;
    int lr = lane & 15, lq = lane >> 4;
    int rbase = rt*64 + (wave & 1)*32;
    int cbase = (wave >> 1)*128;
    const f32x4 zero4 = {0.f,0.f,0.f,0.f};
    f32x4 acc[8][2];
    #pragma unroll
    for(int ct=0;ct<8;ct++){ acc[ct][0] = zero4; acc[ct][1] = zero4; }
    for(int ks=ks0; ks<ks1; ks++){
        int kc = ks*32;
        const float* ar0 = Agf + (size_t)(rbase + lr)*GF_DIM + kc + lq*8;
        const float* ar1 = ar0 + (size_t)16*GF_DIM;
        bf16x8 A0h, A0l, A1h, A1l;
        if(kc + 32 <= GF_DIM){
            #pragma unroll
            for(int t=0;t<8;t++){
                __bf16 h, l;
                split2(ar0[t], h, l); A0h[t] = h; A0l[t] = l;
                split2(ar1[t], h, l); A1h[t] = h; A1l[t] = l;
            }
        } else {
            #pragma unroll
            for(int t=0;t<8;t++){
                int k = kc + lq*8 + t;
                float v0 = 0.f, v1 = 0.f;
                if(k < GF_DIM){ v0 = ar0[t]; v1 = ar1[t]; }
                __bf16 h, l;
                split2(v0, h, l); A0h[t] = h; A0l[t] = l;
                split2(v1, h, l); A1h[t] = h; A1l[t] = l;
            }
        }
        #pragma unroll
        for(int ct=0;ct<8;ct++){
            size_t bo = (size_t)(cbase + ct*16 + lr)*GF_PAD + kc + lq*8;
            bf16x8 Bh = *(const bf16x8*)(Bth + bo);
            bf16x8 Bl = *(const bf16x8*)(Btl + bo);
            acc[ct][0] = __builtin_amdgcn_mfma_f32_16x16x32_bf16(A0h, Bh, acc[ct][0], 0,0,0);
            acc[ct][0] = __builtin_amdgcn_mfma_f32_16x16x32_bf16(A0l, Bh, acc[ct][0], 0,0,0);
            acc[ct][0] = __builtin_amdgcn_mfma_f32_16x16x32_bf16(A0h, Bl, acc[ct][0], 0,0,0);
            acc[ct][1] = __builtin_amdgcn_mfma_f32_16x16x32_bf16(A1h, Bh, acc[ct][1], 0,0,0);
            acc[ct][1] = __builtin_amdgcn_mfma_f32_16x16x32_bf16(A1l, Bh, acc[ct][1], 0,0,0);
            acc[ct][1] = __builtin_amdgcn_mfma_f32_16x16x32_bf16(A1h, Bl, acc[ct][1], 0,0,0);
        }
    }
    float* po = gpart + (size_t)sp*(B_GR*256);
    #pragma unroll
    for(int ct=0;ct<8;ct++)
        #pragma unroll
        for(int s=0;s<2;s++)
            #pragma unroll
            for(int r=0;r<4;r++)
                po[(size_t)(rbase + s*16 + lq*4 + r)*256 + cbase + ct*16 + lr] = acc[ct][s][r];
}

__global__ void k_gene_reduce(const float* __restrict__ gpart, const float* __restrict__ bias,
                              const float* __restrict__ gamma, const float* __restrict__ beta,
                              float* __restrict__ g1){
    int i = blockIdx.x*256 + threadIdx.x;   // B*256
    int c = i & 255;
    float v = bias[c];
    #pragma unroll
    for(int sp=0;sp<8;sp++) v += gpart[(size_t)sp*(B_GR*256) + i];
    v = fmaf(v, gamma[c]*BN_SCALE, beta[c]);
    g1[i] = fmaxf(v, 0.f);
}

// ---------------- FUSED head v3: 8 graphs/block, LDS-staged weights (32 KB chunks) ----
// Weight loads removed from the FMA dependency chain: each 64-K chunk of W is staged
// into LDS via issue-early (4x float4/thread before compute) / write-late (after barrier).
// FMA chains read W from LDS (lanes consecutive -> 2 lanes/bank, conflict-free) and
// activations via LDS broadcast.

__device__ __forceinline__ void load_w4(const float* __restrict__ W, int off, int tid,
                                        float4* t){
    const float4* s = (const float4*)(W + off);
    t[0] = s[tid];
    t[1] = s[tid + 512];
    t[2] = s[tid + 1024];
    t[3] = s[tid + 1536];
}
__device__ __forceinline__ void write_w4(float* sW, int tid, const float4* t){
    float4* d = (float4*)sW;
    d[tid]        = t[0];
    d[tid + 512]  = t[1];
    d[tid + 1024] = t[2];
    d[tid + 1536] = t[3];
}

// one dense stage, N=128: out[g][c] for 8 graphs; each thread: col c, graphs ga,gb
__device__ __forceinline__ void dense_stage128(
        const float* __restrict__ W, int nck, const float* sA, int lda,
        float* sO, int ldo, float* sW, int tid, int c, int ga, int gb,
        float bias_c, float gsc, float bsh, int do_relu){
    float4 t[4];
    load_w4(W, 0, tid, t);
    write_w4(sW, tid, t);
    __syncthreads();
    float a0 = bias_c, a1 = bias_c;
    for(int ck=0; ck<nck; ck++){
        if(ck+1 < nck) load_w4(W, (ck+1)*8192, tid, t);
        const float* aga = sA + ga*lda + ck*64;
        const float* agb = sA + gb*lda + ck*64;
        #pragma unroll
        for(int k=0;k<64;k++){
            float w = sW[k*128 + c];
            a0 = fmaf(aga[k], w, a0);
            a1 = fmaf(agb[k], w, a1);
        }
        __syncthreads();
        if(ck+1 < nck){ write_w4(sW, tid, t); __syncthreads(); }
    }
    a0 = fmaf(a0, gsc, bsh);
    a1 = fmaf(a1, gsc, bsh);
    if(do_relu){ a0 = fmaxf(a0, 0.f); a1 = fmaxf(a1, 0.f); }
    sO[ga*ldo + c] = a0;
    sO[gb*ldo + c] = a1;
}

__global__ __launch_bounds__(512)
void k_head(const uint32* __restrict__ Hh2, const uint32* __restrict__ Hl2,
            const float* __restrict__ g1,
            const float* __restrict__ Wd1, const float* __restrict__ bd1,
            const float* __restrict__ Wd2, const float* __restrict__ bd2,
            const float* __restrict__ Wge2, const float* __restrict__ bge2,
            const float* __restrict__ Wh1, const float* __restrict__ bh1,
            const float* __restrict__ h_g, const float* __restrict__ h_b,
            const float* __restrict__ Wh2, const float* __restrict__ bh2,
            const float* __restrict__ Wh3, const float* __restrict__ bh3,
            float* __restrict__ out){
    __shared__ float sPool[8][256];
    __shared__ float sG1[8][256];
    __shared__ float sT1[8][128];
    __shared__ float sComb[8][256];
    __shared__ float sZ[8][128];
    __shared__ float sZ2[8][64];
    __shared__ float sW[8192];          // 32 KB weight chunk
    int tid = threadIdx.x;
    int wave = tid >> 6, lane = tid & 63;
    int g0 = blockIdx.x*8;
    // g1 into LDS: 8*256 floats, float4 per thread
    {
        int idx = tid*4;                 // 0..2047
        int g = idx >> 8, c = idx & 255;
        *(float4*)&sG1[g][c] = *(const float4*)&g1[(size_t)(g0+g)*256 + c];
    }
    // pool: wave w owns graph w (64 rows, lane = uint-col)
    {
        size_t base = (size_t)(g0+wave)*4096 + lane;
        float se = 0.f, so = 0.f, me = -3.4e38f, mo = -3.4e38f;
        #pragma unroll 8
        for(int r=0;r<64;r++){
            uint32 h = Hh2[base + r*64];
            uint32 l = Hl2[base + r*64];
            float ve = unpack_even(h) + unpack_even(l);
            float vo = unpack_odd(h)  + unpack_odd(l);
            se += ve; so += vo;
            me = fmaxf(me, ve); mo = fmaxf(mo, vo);
        }
        sPool[wave][2*lane]       = se*(1.f/64.f);
        sPool[wave][2*lane+1]     = so*(1.f/64.f);
        sPool[wave][128+2*lane]   = me;
        sPool[wave][128+2*lane+1] = mo;
    }
    __syncthreads();
    int c = tid & 127, q = tid >> 7;     // q in 0..3 -> graphs 2q, 2q+1
    int ga = 2*q, gb = 2*q + 1;
    // t1 = relu(pool @ Wd1 + bd1)             K=256
    dense_stage128(Wd1, 4, &sPool[0][0], 256, &sT1[0][0], 128, sW, tid, c, ga, gb,
                   bd1[c], 1.f, 0.f, 1);
    // comb[:,0:128] = t1 @ Wd2 + bd2          K=128
    dense_stage128(Wd2, 2, &sT1[0][0], 128, &sComb[0][0], 256, sW, tid, c, ga, gb,
                   bd2[c], 1.f, 0.f, 0);
    // comb[:,128:256] = relu(g1 @ Wge2 + bge2) K=256
    dense_stage128(Wge2, 4, &sG1[0][0], 256, &sComb[0][0] + 128, 256, sW, tid, c, ga, gb,
                   bge2[c], 1.f, 0.f, 1);
    // z = relu(BN(comb @ Wh1 + bh1))          K=256
    dense_stage128(Wh1, 4, &sComb[0][0], 256, &sZ[0][0], 128, sW, tid, c, ga, gb,
                   bh1[c], h_g[c]*BN_SCALE, h_b[c], 1);
    // z2 = relu(z @ Wh2 + bh2)  N=64, K=128 (whole Wh2 = one 32 KB chunk)
    {
        float4 t[4];
        load_w4(Wh2, 0, tid, t);
        write_w4(sW, tid, t);
        __syncthreads();
        int c2 = tid & 63, q2 = tid >> 6;     // q2 = graph
        float a = bh2[c2];
        #pragma unroll
        for(int k=0;k<128;k++)
            a = fmaf(sZ[q2][k], sW[k*64 + c2], a);
        sZ2[q2][c2] = fmaxf(a, 0.f);
    }
    __syncthreads();
    // out = z2 @ Wh3 + bh3 : wave w -> graph w
    {
        float v = sZ2[wave][lane] * Wh3[lane];
        #pragma unroll
        for(int off=32; off; off>>=1) v += __shfl_down(v, off);
        if(lane == 0) out[g0 + wave] = v + bh3[0];
    }
}

// ---------------- launch ----------------

extern "C" void kernel_launch(void* const* d_in, const int* in_sizes, int n_in,
                              void* d_out, int out_size, void* d_ws, size_t ws_size,
                              hipStream_t stream){
    (void)in_sizes; (void)n_in; (void)out_size; (void)ws_size;
    const float* x    = (const float*)d_in[0];
    const float* gf   = (const float*)d_in[1];
    const int*   ei   = (const int*)  d_in[2];
    const float* W_emb= (const float*)d_in[4];
    const float* b_emb= (const float*)d_in[5];
    const float* Wg   = (const float*)d_in[6];
    const float* bg   = (const float*)d_in[7];
    const float* bn_g = (const float*)d_in[8];
    const float* bn_b = (const float*)d_in[9];
    const float* Wd1  = (const float*)d_in[10];
    const float* bd1  = (const float*)d_in[11];
    const float* Wd2  = (const float*)d_in[12];
    const float* bd2  = (const float*)d_in[13];
    const float* Wge1 = (const float*)d_in[14];
    const float* bge1 = (const float*)d_in[15];
    const float* g_g  = (const float*)d_in[16];
    const float* g_b  = (const float*)d_in[17];
    const float* Wge2 = (const float*)d_in[18];
    const float* bge2 = (const float*)d_in[19];
    const float* Wh1  = (const float*)d_in[20];
    const float* bh1  = (const float*)d_in[21];
    const float* h_g  = (const float*)d_in[22];
    const float* h_b  = (const float*)d_in[23];
    const float* Wh2  = (const float*)d_in[24];
    const float* bh2  = (const float*)d_in[25];
    const float* Wh3  = (const float*)d_in[26];
    const float* bh3  = (const float*)d_in[27];
    float* outp = (float*)d_out;

    char* base = (char*)d_ws;
    __bf16* Hh = (__bf16*)base;                              // 32 MiB (ping)
    __bf16* Hl = (__bf16*)(base + (32u<<20));                // 32 MiB
    __bf16* Ph = (__bf16*)(base + (64u<<20));                // 32 MiB (pong)
    __bf16* Pl = (__bf16*)(base + (96u<<20));                // 32 MiB
    // gene scratch inside Hh region (dead before k_emb_mfma runs; stream-ordered):
    float*  gpart  = (float*)base;                           // 16,777,216 B
    __bf16* wge_th = (__bf16*)(base + (17u<<20));            // 2,260,992 B
    __bf16* wge_tl = (__bf16*)(base + (17u<<20) + 2260992);  // ends < 22 MiB
    // tail:
    char* T = base + (128u<<20);
    float* g1   = (float*)T;                                 // 2 MiB
    int* rowptr = (int*)(g1 + B_GR*256);
    int* cursor = rowptr + (N_NODES+1);
    int* csr    = cursor + N_NODES;
    int* bsums  = csr + E_EDGES;
    float* dinv = (float*)(bsums + 128);
    __bf16* wg_th = (__bf16*)(dinv + N_NODES);               // 3*16384
    __bf16* wg_tl = wg_th + 3*16384;
    __bf16* we_th = wg_tl + 3*16384;                         // 128*32
    __bf16* we_tl = we_th + 128*32;

    const int* src = ei;
    const int* dst = ei + E_EDGES;

    // weights split (Wge1 + Wg + Wemb in one launch)
    k_split_weights<<<4624, 256, 0, stream>>>(Wge1, wge_th, wge_tl, Wg, wg_th, wg_tl,
                                              W_emb, we_th, we_tl);

    // gene branch (gpart/wge live in Hh region, consumed before k_emb)
    k_gemm_gf_mfma<<<256, 256, 0, stream>>>(gf, wge_th, wge_tl, gpart);
    k_gene_reduce <<<(B_GR*256)/256, 256, 0, stream>>>(gpart, bge1, g_g, g_b, g1);

    // graph prep
    k_zero_int   <<<N_NODES/256, 256, 0, stream>>>(cursor, N_NODES);
    k_count      <<<E_EDGES/256, 256, 0, stream>>>(dst, cursor);
    k_scan1      <<<128, 1024, 0, stream>>>(cursor, bsums);
    k_scan2      <<<1, 128, 0, stream>>>(bsums);
    k_scan3      <<<128, 1024, 0, stream>>>(cursor, bsums, rowptr);
    k_dinv_cursor<<<N_NODES/256, 256, 0, stream>>>(rowptr, dinv, cursor);
    k_fill       <<<E_EDGES/256, 256, 0, stream>>>(src, dst, cursor, csr);

    // embedding (fused x split)
    k_emb_mfma<<<N_NODES/128, 256, 0, stream>>>(x, we_th, we_tl, b_emb,
                                                (uint32*)Hh, (uint32*)Hl);

    // 3 fused GCN layers, ping-pong (Hh,Hl) <-> (Ph,Pl)
    uint32 *curh = (uint32*)Hh, *curl = (uint32*)Hl;
    uint32 *outh = (uint32*)Ph, *outl = (uint32*)Pl;
    for(int i=0;i<3;i++){
        k_layer<<<N_NODES/128, 512, 0, stream>>>((const __bf16*)curh, (const __bf16*)curl,
                                                 dinv, rowptr, csr,
                                                 wg_th + i*16384, wg_tl + i*16384,
                                                 bg + i*H_DIM, bn_g + i*H_DIM, bn_b + i*H_DIM,
                                                 outh, outl, i > 0);
        uint32* th = curh; curh = outh; outh = th;
        uint32* tl = curl; curl = outl; outl = tl;
    }

    // fused head v3 (LDS-staged weights); final H is in (curh, curl)
    k_head<<<B_GR/8, 512, 0, stream>>>(curh, curl, g1,
                                       Wd1, bd1, Wd2, bd2, Wge2, bge2,
                                       Wh1, bh1, h_g, h_b, Wh2, bh2, Wh3, bh3, outp);
}